// Round 1
// baseline (183.711 us; speedup 1.0000x reference)
//
#include <hip/hip_runtime.h>
#include <hip/hip_bf16.h>

typedef __bf16 bf16x8 __attribute__((ext_vector_type(8)));
typedef float f32x4 __attribute__((ext_vector_type(4)));

__device__ inline unsigned short f2bf(float f) {
    __hip_bfloat16 h = __float2bfloat16(f);
    return __builtin_bit_cast(unsigned short, h);
}

// ---------------- fp32 -> bf16 conversion (vectorized, 4 elems/thread) ----------------
__global__ __launch_bounds__(256) void cvt_f32_bf16(const float* __restrict__ in,
                                                    unsigned short* __restrict__ out, int n4) {
    int i = blockIdx.x * blockDim.x + threadIdx.x;
    if (i < n4) {
        float4 v = reinterpret_cast<const float4*>(in)[i];
        ushort4 o;
        o.x = f2bf(v.x); o.y = f2bf(v.y); o.z = f2bf(v.z); o.w = f2bf(v.w);
        reinterpret_cast<ushort4*>(out)[i] = o;
    }
}

// ---------------- C = A(MxK) * B(NxK)^T, bf16 in/out, fp32 accum, scale folded -------
// 128x128 tile, 4 waves (2x2), each wave 64x64 = 4x4 frags of 16x16, BK=32.
__global__ __launch_bounds__(256) void gemm_bt(const unsigned short* __restrict__ A,
                                               const unsigned short* __restrict__ B,
                                               unsigned short* __restrict__ C,
                                               int M, int N, int K, float scale) {
    __shared__ __align__(16) unsigned short sA[128 * 40];  // +8 pad: 80B stride, 2-way max
    __shared__ __align__(16) unsigned short sB[128 * 40];
    const int tid  = threadIdx.x;
    const int lane = tid & 63;
    const int wave = tid >> 6;
    const int wr = wave >> 1, wc = wave & 1;
    const int bm = blockIdx.x * 128;
    const int bn = blockIdx.y * 128;
    const int tr = tid >> 1, th = (tid & 1) * 16;
    const int rl = lane & 15;
    const int kq = (lane >> 4) * 8;

    f32x4 acc[4][4];
#pragma unroll
    for (int m = 0; m < 4; ++m)
#pragma unroll
        for (int n = 0; n < 4; ++n) acc[m][n] = (f32x4){0.f, 0.f, 0.f, 0.f};

    for (int k0 = 0; k0 < K; k0 += 32) {
        uint4 a0 = *reinterpret_cast<const uint4*>(&A[(size_t)(bm + tr) * K + k0 + th]);
        uint4 a1 = *reinterpret_cast<const uint4*>(&A[(size_t)(bm + tr) * K + k0 + th + 8]);
        uint4 b0 = *reinterpret_cast<const uint4*>(&B[(size_t)(bn + tr) * K + k0 + th]);
        uint4 b1 = *reinterpret_cast<const uint4*>(&B[(size_t)(bn + tr) * K + k0 + th + 8]);
        __syncthreads();  // WAR: previous iter's fragment reads done
        *reinterpret_cast<uint4*>(&sA[tr * 40 + th])     = a0;
        *reinterpret_cast<uint4*>(&sA[tr * 40 + th + 8]) = a1;
        *reinterpret_cast<uint4*>(&sB[tr * 40 + th])     = b0;
        *reinterpret_cast<uint4*>(&sB[tr * 40 + th + 8]) = b1;
        __syncthreads();

        bf16x8 af[4], bfv[4];
#pragma unroll
        for (int m = 0; m < 4; ++m)
            af[m] = __builtin_bit_cast(bf16x8,
                *reinterpret_cast<const uint4*>(&sA[(wr * 64 + m * 16 + rl) * 40 + kq]));
#pragma unroll
        for (int n = 0; n < 4; ++n)
            bfv[n] = __builtin_bit_cast(bf16x8,
                *reinterpret_cast<const uint4*>(&sB[(wc * 64 + n * 16 + rl) * 40 + kq]));
#pragma unroll
        for (int m = 0; m < 4; ++m)
#pragma unroll
            for (int n = 0; n < 4; ++n)
                acc[m][n] = __builtin_amdgcn_mfma_f32_16x16x32_bf16(af[m], bfv[n], acc[m][n], 0, 0, 0);
    }

    const int rq = (lane >> 4) * 4;
#pragma unroll
    for (int m = 0; m < 4; ++m) {
        int r = bm + wr * 64 + m * 16 + rq;
#pragma unroll
        for (int n = 0; n < 4; ++n) {
            int c = bn + wc * 64 + n * 16 + rl;
#pragma unroll
            for (int reg = 0; reg < 4; ++reg)
                C[(size_t)(r + reg) * N + c] = f2bf(acc[m][n][reg] * scale);
        }
    }
}

// ---------------- fused flash attention with ALiBi-abs bias --------------------------
// grid: (32 q-tiles, 8 heads, 4 batch). block: 256 = 4 waves, each wave 16 q-rows.
// KV tile = 64. Q pre-scaled by 0.125 (folded into projection).
__global__ __launch_bounds__(256) void attn_fwd(const unsigned short* __restrict__ Q,
                                                const unsigned short* __restrict__ Kb,
                                                const unsigned short* __restrict__ Vb,
                                                const float* __restrict__ pos,
                                                float* __restrict__ Out) {
    __shared__ __align__(16) unsigned short sK[64 * 72];    // [j][d], 144B stride
    __shared__ __align__(16) unsigned short sVt[64 * 72];   // [d][j] (transposed V)
    __shared__ __align__(16) unsigned short sP[4 * 16 * 72];// per-wave P re-layout
    __shared__ float sPos[64];

    const int tid  = threadIdx.x;
    const int lane = tid & 63;
    const int wave = tid >> 6;
    const int b = blockIdx.z, h = blockIdx.y;
    const int q0 = blockIdx.x * 64;
    const int rl = lane & 15;
    const int kq = (lane >> 4) * 8;
    const int rq = (lane >> 4) * 4;
    const size_t rowbase = (size_t)b * 2048;
    const int hc = h * 64;
    const float slope = ldexpf(1.0f, -(h + 1));  // HEADS=8 -> 2^-(h+1)

    // Q fragments stay in registers: A-frag row = rl (wave's 16 rows), k = d
    bf16x8 qf[2];
    {
        size_t qoff = (rowbase + q0 + wave * 16 + rl) * 512 + hc;
        qf[0] = __builtin_bit_cast(bf16x8, *reinterpret_cast<const uint4*>(&Q[qoff + kq]));
        qf[1] = __builtin_bit_cast(bf16x8, *reinterpret_cast<const uint4*>(&Q[qoff + 32 + kq]));
    }
    float pi[4];
#pragma unroll
    for (int r = 0; r < 4; ++r) pi[r] = pos[rowbase + q0 + wave * 16 + rq + r];

    float mrun[4], lrun[4];
    f32x4 o[4];
#pragma unroll
    for (int r = 0; r < 4; ++r) { mrun[r] = -1e30f; lrun[r] = 0.f; }
#pragma unroll
    for (int d = 0; d < 4; ++d) o[d] = (f32x4){0.f, 0.f, 0.f, 0.f};

    const int sr = tid >> 2;         // staging: 64 rows x 4 chunks
    const int sq = (tid & 3) * 16;

    for (int j0 = 0; j0 < 2048; j0 += 64) {
        size_t goff = (rowbase + j0 + sr) * 512 + hc + sq;
        uint4 k0v = *reinterpret_cast<const uint4*>(&Kb[goff]);
        uint4 k1v = *reinterpret_cast<const uint4*>(&Kb[goff + 8]);
        uint4 v0v = *reinterpret_cast<const uint4*>(&Vb[goff]);
        uint4 v1v = *reinterpret_cast<const uint4*>(&Vb[goff + 8]);
        float pj = (tid < 64) ? pos[rowbase + j0 + tid] : 0.f;
        __syncthreads();  // WAR on sK/sVt
        *reinterpret_cast<uint4*>(&sK[sr * 72 + sq])     = k0v;
        *reinterpret_cast<uint4*>(&sK[sr * 72 + sq + 8]) = k1v;
        union { uint4 u; unsigned short s[8]; } w0, w1;
        w0.u = v0v; w1.u = v1v;
#pragma unroll
        for (int e = 0; e < 8; ++e) {
            sVt[(sq + e) * 72 + sr]     = w0.s[e];
            sVt[(sq + 8 + e) * 72 + sr] = w1.s[e];
        }
        if (tid < 64) sPos[tid] = pj;
        __syncthreads();

        // S = Q K^T  (C: row=(lane>>4)*4+reg = q-row, col=lane&15 = j-in-frag)
        f32x4 s[4];
#pragma unroll
        for (int jf = 0; jf < 4; ++jf) s[jf] = (f32x4){0.f, 0.f, 0.f, 0.f};
#pragma unroll
        for (int ks = 0; ks < 2; ++ks) {
#pragma unroll
            for (int jf = 0; jf < 4; ++jf) {
                bf16x8 kf = __builtin_bit_cast(bf16x8,
                    *reinterpret_cast<const uint4*>(&sK[(jf * 16 + rl) * 72 + ks * 32 + kq]));
                s[jf] = __builtin_amdgcn_mfma_f32_16x16x32_bf16(qf[ks], kf, s[jf], 0, 0, 0);
            }
        }

        // bias + online softmax
        float mx[4];
#pragma unroll
        for (int r = 0; r < 4; ++r) mx[r] = -1e30f;
#pragma unroll
        for (int jf = 0; jf < 4; ++jf) {
            float pjv = sPos[jf * 16 + rl];
#pragma unroll
            for (int r = 0; r < 4; ++r) {
                float v = s[jf][r] - slope * fabsf(pjv - pi[r]);
                s[jf][r] = v;
                mx[r] = fmaxf(mx[r], v);
            }
        }
#pragma unroll
        for (int r = 0; r < 4; ++r) {
#pragma unroll
            for (int off = 8; off >= 1; off >>= 1)
                mx[r] = fmaxf(mx[r], __shfl_xor(mx[r], off, 64));
        }
        float alpha[4];
#pragma unroll
        for (int r = 0; r < 4; ++r) {
            float mn = fmaxf(mrun[r], mx[r]);
            alpha[r] = __expf(mrun[r] - mn);
            mrun[r] = mn;
        }
        float ls[4] = {0.f, 0.f, 0.f, 0.f};
#pragma unroll
        for (int jf = 0; jf < 4; ++jf) {
#pragma unroll
            for (int r = 0; r < 4; ++r) {
                float p = __expf(s[jf][r] - mrun[r]);
                s[jf][r] = p;
                ls[r] += p;
            }
        }
#pragma unroll
        for (int r = 0; r < 4; ++r) {
            float t = ls[r];
#pragma unroll
            for (int off = 8; off >= 1; off >>= 1) t += __shfl_xor(t, off, 64);
            lrun[r] = lrun[r] * alpha[r] + t;
        }
#pragma unroll
        for (int d = 0; d < 4; ++d)
#pragma unroll
            for (int r = 0; r < 4; ++r) o[d][r] *= alpha[r];

        // P -> LDS (wave-private), re-read as A-fragment
#pragma unroll
        for (int jf = 0; jf < 4; ++jf)
#pragma unroll
            for (int r = 0; r < 4; ++r)
                sP[wave * 1152 + (rq + r) * 72 + jf * 16 + rl] = f2bf(s[jf][r]);

#pragma unroll
        for (int ks = 0; ks < 2; ++ks) {
            bf16x8 pf = __builtin_bit_cast(bf16x8,
                *reinterpret_cast<const uint4*>(&sP[wave * 1152 + rl * 72 + ks * 32 + kq]));
#pragma unroll
            for (int d = 0; d < 4; ++d) {
                bf16x8 vf = __builtin_bit_cast(bf16x8,
                    *reinterpret_cast<const uint4*>(&sVt[(d * 16 + rl) * 72 + ks * 32 + kq]));
                o[d] = __builtin_amdgcn_mfma_f32_16x16x32_bf16(pf, vf, o[d], 0, 0, 0);
            }
        }
    }

#pragma unroll
    for (int r = 0; r < 4; ++r) {
        float inv = 1.0f / lrun[r];
        size_t orow = (rowbase + q0 + wave * 16 + rq + r) * 512 + hc;
#pragma unroll
        for (int d = 0; d < 4; ++d)
            Out[orow + d * 16 + rl] = o[d][r] * inv;
    }
}

extern "C" void kernel_launch(void* const* d_in, const int* in_sizes, int n_in,
                              void* d_out, int out_size, void* d_ws, size_t ws_size,
                              hipStream_t stream) {
    const float* x   = (const float*)d_in[0];
    const float* pos = (const float*)d_in[1];
    const float* Wq  = (const float*)d_in[2];
    const float* Wk  = (const float*)d_in[3];
    float* out = (float*)d_out;

    // workspace layout (bf16 elements): x 4.19M | Wq 262K | Wk 262K | Q 4.19M | K 4.19M  (~25MB)
    unsigned short* xb  = (unsigned short*)d_ws;
    unsigned short* wqb = xb  + 4194304;
    unsigned short* wkb = wqb + 262144;
    unsigned short* Qb  = wkb + 262144;
    unsigned short* Kbf = Qb  + 4194304;

    cvt_f32_bf16<<<dim3(4096), dim3(256), 0, stream>>>(x,  xb,  4194304 / 4);
    cvt_f32_bf16<<<dim3(256),  dim3(256), 0, stream>>>(Wq, wqb, 262144 / 4);
    cvt_f32_bf16<<<dim3(256),  dim3(256), 0, stream>>>(Wk, wkb, 262144 / 4);

    // Q = (x Wq^T) * 0.125 (SCALE folded, exact pow2); K = x Wk^T
    gemm_bt<<<dim3(64, 4), dim3(256), 0, stream>>>(xb, wqb, Qb,  8192, 512, 512, 0.125f);
    gemm_bt<<<dim3(64, 4), dim3(256), 0, stream>>>(xb, wkb, Kbf, 8192, 512, 512, 1.0f);

    attn_fwd<<<dim3(32, 8, 4), dim3(256), 0, stream>>>(Qb, Kbf, xb, pos, out);
}

// Round 2
// 134.928 us; speedup vs baseline: 1.3615x; 1.3615x over previous
//
#include <hip/hip_runtime.h>
#include <hip/hip_bf16.h>

typedef __bf16 bf16x8 __attribute__((ext_vector_type(8)));
typedef float f32x4 __attribute__((ext_vector_type(4)));

__device__ inline unsigned short f2bf(float f) {
    __hip_bfloat16 h = __float2bfloat16(f);
    return __builtin_bit_cast(unsigned short, h);
}
__device__ inline unsigned pk2bf(float a, float b) {
    return (unsigned)f2bf(a) | ((unsigned)f2bf(b) << 16);
}

// ---------------- fp32 -> bf16 conversion (vectorized, 4 elems/thread) ----------------
__global__ __launch_bounds__(256) void cvt_f32_bf16(const float* __restrict__ in,
                                                    unsigned short* __restrict__ out, int n4) {
    int i = blockIdx.x * blockDim.x + threadIdx.x;
    if (i < n4) {
        float4 v = reinterpret_cast<const float4*>(in)[i];
        ushort4 o;
        o.x = f2bf(v.x); o.y = f2bf(v.y); o.z = f2bf(v.z); o.w = f2bf(v.w);
        reinterpret_cast<ushort4*>(out)[i] = o;
    }
}

// ---------------- V transpose: x[b][n][hc+d] (f32) -> Vt[b*8+h][d][n] (bf16) ---------
// grid (8 ntiles, 8 h, 4 b), block 256 = 4 waves; wave handles 64 consecutive n.
__global__ __launch_bounds__(256) void xpose_v(const float* __restrict__ x,
                                               unsigned short* __restrict__ Vt) {
    const int tid = threadIdx.x;
    const int lane = tid & 63, w = tid >> 6;
    const int b = blockIdx.z, h = blockIdx.y;
    const int n = blockIdx.x * 256 + w * 64 + lane;
    const size_t xrow = ((size_t)b * 2048 + n) * 512 + h * 64;
    const size_t vbase = ((size_t)(b * 8 + h) * 64) * 2048 + n;
#pragma unroll
    for (int d0 = 0; d0 < 64; d0 += 4) {
        float4 v = *reinterpret_cast<const float4*>(&x[xrow + d0]);
        Vt[vbase + (size_t)(d0 + 0) * 2048] = f2bf(v.x);
        Vt[vbase + (size_t)(d0 + 1) * 2048] = f2bf(v.y);
        Vt[vbase + (size_t)(d0 + 2) * 2048] = f2bf(v.z);
        Vt[vbase + (size_t)(d0 + 3) * 2048] = f2bf(v.w);
    }
}

// ---------------- C = A(MxK) * B(NxK)^T, bf16 in/out, fp32 accum, scale folded -------
__global__ __launch_bounds__(256) void gemm_bt(const unsigned short* __restrict__ A,
                                               const unsigned short* __restrict__ B,
                                               unsigned short* __restrict__ C,
                                               int M, int N, int K, float scale) {
    __shared__ __align__(16) unsigned short sA[128 * 40];
    __shared__ __align__(16) unsigned short sB[128 * 40];
    const int tid  = threadIdx.x;
    const int lane = tid & 63;
    const int wave = tid >> 6;
    const int wr = wave >> 1, wc = wave & 1;
    const int bm = blockIdx.x * 128;
    const int bn = blockIdx.y * 128;
    const int tr = tid >> 1, th = (tid & 1) * 16;
    const int rl = lane & 15;
    const int kq = (lane >> 4) * 8;

    f32x4 acc[4][4];
#pragma unroll
    for (int m = 0; m < 4; ++m)
#pragma unroll
        for (int n = 0; n < 4; ++n) acc[m][n] = (f32x4){0.f, 0.f, 0.f, 0.f};

    for (int k0 = 0; k0 < K; k0 += 32) {
        uint4 a0 = *reinterpret_cast<const uint4*>(&A[(size_t)(bm + tr) * K + k0 + th]);
        uint4 a1 = *reinterpret_cast<const uint4*>(&A[(size_t)(bm + tr) * K + k0 + th + 8]);
        uint4 b0 = *reinterpret_cast<const uint4*>(&B[(size_t)(bn + tr) * K + k0 + th]);
        uint4 b1 = *reinterpret_cast<const uint4*>(&B[(size_t)(bn + tr) * K + k0 + th + 8]);
        __syncthreads();
        *reinterpret_cast<uint4*>(&sA[tr * 40 + th])     = a0;
        *reinterpret_cast<uint4*>(&sA[tr * 40 + th + 8]) = a1;
        *reinterpret_cast<uint4*>(&sB[tr * 40 + th])     = b0;
        *reinterpret_cast<uint4*>(&sB[tr * 40 + th + 8]) = b1;
        __syncthreads();

        bf16x8 af[4], bfv[4];
#pragma unroll
        for (int m = 0; m < 4; ++m)
            af[m] = __builtin_bit_cast(bf16x8,
                *reinterpret_cast<const uint4*>(&sA[(wr * 64 + m * 16 + rl) * 40 + kq]));
#pragma unroll
        for (int n = 0; n < 4; ++n)
            bfv[n] = __builtin_bit_cast(bf16x8,
                *reinterpret_cast<const uint4*>(&sB[(wc * 64 + n * 16 + rl) * 40 + kq]));
#pragma unroll
        for (int m = 0; m < 4; ++m)
#pragma unroll
            for (int n = 0; n < 4; ++n)
                acc[m][n] = __builtin_amdgcn_mfma_f32_16x16x32_bf16(af[m], bfv[n], acc[m][n], 0, 0, 0);
    }

    const int rq = (lane >> 4) * 4;
#pragma unroll
    for (int m = 0; m < 4; ++m) {
        int r = bm + wr * 64 + m * 16 + rq;
#pragma unroll
        for (int n = 0; n < 4; ++n) {
            int c = bn + wc * 64 + n * 16 + rl;
#pragma unroll
            for (int reg = 0; reg < 4; ++reg)
                C[(size_t)(r + reg) * N + c] = f2bf(acc[m][n][reg] * scale);
        }
    }
}

// ---------------- fused flash attention, swapped-QK^T, per-lane softmax --------------
// grid: (32 q-tiles, 8 heads, 4 batch). block: 256 = 4 waves, each wave 16 q-rows.
// KV tile = 64. SCALE folded into Q. S^T layout: lane rl = q-row, (g=lane>>4, reg r,
// frag jf) -> j = 16*jf + 4*g + r.
__global__ __launch_bounds__(256) void attn_fwd(const unsigned short* __restrict__ Q,
                                                const unsigned short* __restrict__ Kb,
                                                const unsigned short* __restrict__ Vt,
                                                const float* __restrict__ pos,
                                                float* __restrict__ Out) {
    __shared__ __align__(16) unsigned short sK[64 * 72];   // [j][d], stride 144B
    __shared__ __align__(16) unsigned short sV[64 * 72];   // [d][j], stride 144B
    __shared__ __align__(16) unsigned int   sP[4 * 16 * 36]; // per-wave [q=16][j/2 dwords, stride 36]
    __shared__ __align__(16) float sPos[64];

    const int tid  = threadIdx.x;
    const int lane = tid & 63;
    const int wave = tid >> 6;
    const int b = blockIdx.z, h = blockIdx.y;
    const int q0 = blockIdx.x * 64;
    const int rl = lane & 15;
    const int g  = lane >> 4;
    const int kq = g * 8;
    const size_t rowbase = (size_t)b * 2048;
    const int hc = h * 64;
    const int bh = b * 8 + h;
    const float slope = ldexpf(1.0f, -(h + 1));

    // Q fragments (B-operand for swapped QK^T): lane supplies Q[q=rl][d=ks*32+kq+e]
    bf16x8 qf[2];
    {
        size_t qoff = (rowbase + q0 + wave * 16 + rl) * 512 + hc;
        qf[0] = __builtin_bit_cast(bf16x8, *reinterpret_cast<const uint4*>(&Q[qoff + kq]));
        qf[1] = __builtin_bit_cast(bf16x8, *reinterpret_cast<const uint4*>(&Q[qoff + 32 + kq]));
    }
    const float pi = pos[rowbase + q0 + wave * 16 + rl];

    float mrun = -1e30f, lrun = 0.f;
    f32x4 o[4];
#pragma unroll
    for (int d = 0; d < 4; ++d) o[d] = (f32x4){0.f, 0.f, 0.f, 0.f};

    const int sr = tid >> 2;          // 64 rows
    const int sq = (tid & 3) * 16;    // 4 chunks of 16

    // prefetch tile 0
    uint4 ck0, ck1, cv0, cv1;
    float cpj;
    {
        size_t kgo = (rowbase + sr) * 512 + hc + sq;
        size_t vgo = ((size_t)bh * 64 + sr) * 2048 + sq;
        ck0 = *reinterpret_cast<const uint4*>(&Kb[kgo]);
        ck1 = *reinterpret_cast<const uint4*>(&Kb[kgo + 8]);
        cv0 = *reinterpret_cast<const uint4*>(&Vt[vgo]);
        cv1 = *reinterpret_cast<const uint4*>(&Vt[vgo + 8]);
        cpj = (tid < 64) ? pos[rowbase + tid] : 0.f;
    }

    for (int j0 = 0; j0 < 2048; j0 += 64) {
        __syncthreads();  // WAR: all waves done reading previous tile
        *reinterpret_cast<uint4*>(&sK[sr * 72 + sq])     = ck0;
        *reinterpret_cast<uint4*>(&sK[sr * 72 + sq + 8]) = ck1;
        *reinterpret_cast<uint4*>(&sV[sr * 72 + sq])     = cv0;
        *reinterpret_cast<uint4*>(&sV[sr * 72 + sq + 8]) = cv1;
        if (tid < 64) sPos[tid] = cpj;
        if (j0 + 64 < 2048) {  // issue next-tile loads; latency hides under compute
            size_t kgn = (rowbase + j0 + 64 + sr) * 512 + hc + sq;
            size_t vgn = ((size_t)bh * 64 + sr) * 2048 + j0 + 64 + sq;
            ck0 = *reinterpret_cast<const uint4*>(&Kb[kgn]);
            ck1 = *reinterpret_cast<const uint4*>(&Kb[kgn + 8]);
            cv0 = *reinterpret_cast<const uint4*>(&Vt[vgn]);
            cv1 = *reinterpret_cast<const uint4*>(&Vt[vgn + 8]);
            cpj = (tid < 64) ? pos[rowbase + j0 + 64 + tid] : 0.f;
        }
        __syncthreads();  // tile ready

        // S^T = K Q^T : D[j][q], row j=(g)*4+r (+16jf), col q=rl
        f32x4 s[4];
#pragma unroll
        for (int jf = 0; jf < 4; ++jf) s[jf] = (f32x4){0.f, 0.f, 0.f, 0.f};
#pragma unroll
        for (int ks = 0; ks < 2; ++ks) {
#pragma unroll
            for (int jf = 0; jf < 4; ++jf) {
                bf16x8 kf = __builtin_bit_cast(bf16x8,
                    *reinterpret_cast<const uint4*>(&sK[(jf * 16 + rl) * 72 + ks * 32 + kq]));
                s[jf] = __builtin_amdgcn_mfma_f32_16x16x32_bf16(kf, qf[ks], s[jf], 0, 0, 0);
            }
        }

        // bias + per-lane (q=rl) online softmax over 16 local j + 2 cross-group shfl
        float mx = -1e30f;
#pragma unroll
        for (int jf = 0; jf < 4; ++jf) {
            f32x4 pj = *reinterpret_cast<const f32x4*>(&sPos[jf * 16 + 4 * g]);
#pragma unroll
            for (int r = 0; r < 4; ++r) {
                float v = s[jf][r] - slope * fabsf(pj[r] - pi);
                s[jf][r] = v;
                mx = fmaxf(mx, v);
            }
        }
        mx = fmaxf(mx, __shfl_xor(mx, 16, 64));
        mx = fmaxf(mx, __shfl_xor(mx, 32, 64));
        float mnew = fmaxf(mrun, mx);
        float alpha = __expf(mrun - mnew);
        mrun = mnew;
        float ls = 0.f;
#pragma unroll
        for (int jf = 0; jf < 4; ++jf)
#pragma unroll
            for (int r = 0; r < 4; ++r) {
                float p = __expf(s[jf][r] - mnew);
                s[jf][r] = p;
                ls += p;
            }
        ls += __shfl_xor(ls, 16, 64);
        ls += __shfl_xor(ls, 32, 64);
        lrun = lrun * alpha + ls;

        // pack P (bf16 pairs, consecutive j) -> sP[q][j/2]; stride 36 dwords
        {
            const int pbase = wave * 576 + rl * 36;
#pragma unroll
            for (int jf = 0; jf < 4; ++jf) {
                uint2 w;
                w.x = pk2bf(s[jf][0], s[jf][1]);
                w.y = pk2bf(s[jf][2], s[jf][3]);
                *reinterpret_cast<uint2*>(&sP[pbase + 8 * jf + 2 * g]) = w;
            }
        }

        // rescale O by alpha of its rows q = 4g+r (alpha lives at lane rl=q, group 0)
        float ar[4];
#pragma unroll
        for (int r = 0; r < 4; ++r) ar[r] = __shfl(alpha, 4 * g + r, 64);
#pragma unroll
        for (int d = 0; d < 4; ++d)
#pragma unroll
            for (int r = 0; r < 4; ++r) o[d][r] *= ar[r];

        // PV: A = P[q=rl][j=32ks+8g+e], B = Vt[d][j] -> O[q][d]
#pragma unroll
        for (int ks = 0; ks < 2; ++ks) {
            bf16x8 pf = __builtin_bit_cast(bf16x8,
                *reinterpret_cast<const uint4*>(&sP[wave * 576 + rl * 36 + 16 * ks + 4 * g]));
#pragma unroll
            for (int d = 0; d < 4; ++d) {
                bf16x8 vf = __builtin_bit_cast(bf16x8,
                    *reinterpret_cast<const uint4*>(&sV[(d * 16 + rl) * 72 + ks * 32 + kq]));
                o[d] = __builtin_amdgcn_mfma_f32_16x16x32_bf16(pf, vf, o[d], 0, 0, 0);
            }
        }
    }

    float linv[4];
#pragma unroll
    for (int r = 0; r < 4; ++r) linv[r] = 1.0f / __shfl(lrun, 4 * g + r, 64);
#pragma unroll
    for (int r = 0; r < 4; ++r) {
        size_t orow = (rowbase + q0 + wave * 16 + 4 * g + r) * 512 + hc;
#pragma unroll
        for (int d = 0; d < 4; ++d)
            Out[orow + d * 16 + rl] = o[d][r] * linv[r];
    }
}

extern "C" void kernel_launch(void* const* d_in, const int* in_sizes, int n_in,
                              void* d_out, int out_size, void* d_ws, size_t ws_size,
                              hipStream_t stream) {
    const float* x   = (const float*)d_in[0];
    const float* pos = (const float*)d_in[1];
    const float* Wq  = (const float*)d_in[2];
    const float* Wk  = (const float*)d_in[3];
    float* out = (float*)d_out;

    // ws (bf16 elems): x 4.19M | Wq 262K | Wk 262K | Q 4.19M | K 4.19M | Vt 4.19M (~35MB)
    unsigned short* xb  = (unsigned short*)d_ws;
    unsigned short* wqb = xb  + 4194304;
    unsigned short* wkb = wqb + 262144;
    unsigned short* Qb  = wkb + 262144;
    unsigned short* Kbf = Qb  + 4194304;
    unsigned short* Vtb = Kbf + 4194304;

    cvt_f32_bf16<<<dim3(4096), dim3(256), 0, stream>>>(x,  xb,  4194304 / 4);
    cvt_f32_bf16<<<dim3(256),  dim3(256), 0, stream>>>(Wq, wqb, 262144 / 4);
    cvt_f32_bf16<<<dim3(256),  dim3(256), 0, stream>>>(Wk, wkb, 262144 / 4);
    xpose_v<<<dim3(8, 8, 4), dim3(256), 0, stream>>>(x, Vtb);

    gemm_bt<<<dim3(64, 4), dim3(256), 0, stream>>>(xb, wqb, Qb,  8192, 512, 512, 0.125f);
    gemm_bt<<<dim3(64, 4), dim3(256), 0, stream>>>(xb, wkb, Kbf, 8192, 512, 512, 1.0f);

    attn_fwd<<<dim3(32, 8, 4), dim3(256), 0, stream>>>(Qb, Kbf, Vtb, pos, out);
}

// Round 5
// 97.831 us; speedup vs baseline: 1.8778x; 1.3792x over previous
//
#include <hip/hip_runtime.h>
#include <hip/hip_bf16.h>

typedef __bf16 bf16x8 __attribute__((ext_vector_type(8)));
typedef float f32x4 __attribute__((ext_vector_type(4)));
typedef float f32x16 __attribute__((ext_vector_type(16)));

__device__ inline unsigned short f2bf(float f) {
    __hip_bfloat16 h = __float2bfloat16(f);
    return __builtin_bit_cast(unsigned short, h);
}
__device__ inline unsigned pk2bf(float a, float b) {
    return (unsigned)f2bf(a) | ((unsigned)f2bf(b) << 16);
}

// ---------------- V transpose: x[b][n][hc+d] (f32) -> Vt[b*8+h][d][n] (bf16) ---------
__global__ __launch_bounds__(256) void xpose_v(const float* __restrict__ x,
                                               unsigned short* __restrict__ Vt) {
    const int tid = threadIdx.x;
    const int lane = tid & 63, w = tid >> 6;
    const int b = blockIdx.z, h = blockIdx.y;
    const int n = blockIdx.x * 256 + w * 64 + lane;
    const size_t xrow = ((size_t)b * 2048 + n) * 512 + h * 64;
    const size_t vbase = ((size_t)(b * 8 + h) * 64) * 2048 + n;
#pragma unroll
    for (int d0 = 0; d0 < 64; d0 += 4) {
        float4 v = *reinterpret_cast<const float4*>(&x[xrow + d0]);
        Vt[vbase + (size_t)(d0 + 0) * 2048] = f2bf(v.x);
        Vt[vbase + (size_t)(d0 + 1) * 2048] = f2bf(v.y);
        Vt[vbase + (size_t)(d0 + 2) * 2048] = f2bf(v.z);
        Vt[vbase + (size_t)(d0 + 3) * 2048] = f2bf(v.w);
    }
}

// ---------------- fused Q/K projection: C = x(8192x512) * W^T, f32 in, bf16 out ------
// grid (64, 8): by<4 -> Wq (scale 0.125 folded), by>=4 -> Wk. 128x128 tile, 4 waves.
__global__ __launch_bounds__(256) void gemm_qk(const float* __restrict__ x,
                                               const float* __restrict__ Wq,
                                               const float* __restrict__ Wk,
                                               unsigned short* __restrict__ Qb,
                                               unsigned short* __restrict__ Kb) {
    __shared__ __align__(16) unsigned short sA[128 * 40];
    __shared__ __align__(16) unsigned short sB[128 * 40];
    const int tid  = threadIdx.x;
    const int lane = tid & 63;
    const int wave = tid >> 6;
    const int wr = wave >> 1, wc = wave & 1;
    const int bm = blockIdx.x * 128;
    const int by = blockIdx.y;
    const float* __restrict__ Bsrc = (by < 4) ? Wq : Wk;
    unsigned short* __restrict__ C = (by < 4) ? Qb : Kb;
    const int bn = (by & 3) * 128;
    const float scale = (by < 4) ? 0.125f : 1.0f;
    const int tr = tid >> 1, th = (tid & 1) * 16;
    const int rl = lane & 15;
    const int kq = (lane >> 4) * 8;

    f32x4 acc[4][4];
#pragma unroll
    for (int m = 0; m < 4; ++m)
#pragma unroll
        for (int n = 0; n < 4; ++n) acc[m][n] = (f32x4){0.f, 0.f, 0.f, 0.f};

    for (int k0 = 0; k0 < 512; k0 += 32) {
        const float* ap = &x[(size_t)(bm + tr) * 512 + k0 + th];
        const float* bp = &Bsrc[(size_t)(bn + tr) * 512 + k0 + th];
        float4 a0 = *reinterpret_cast<const float4*>(ap);
        float4 a1 = *reinterpret_cast<const float4*>(ap + 4);
        float4 a2 = *reinterpret_cast<const float4*>(ap + 8);
        float4 a3 = *reinterpret_cast<const float4*>(ap + 12);
        float4 b0 = *reinterpret_cast<const float4*>(bp);
        float4 b1 = *reinterpret_cast<const float4*>(bp + 4);
        float4 b2 = *reinterpret_cast<const float4*>(bp + 8);
        float4 b3 = *reinterpret_cast<const float4*>(bp + 12);
        uint4 pa0 = {pk2bf(a0.x, a0.y), pk2bf(a0.z, a0.w), pk2bf(a1.x, a1.y), pk2bf(a1.z, a1.w)};
        uint4 pa1 = {pk2bf(a2.x, a2.y), pk2bf(a2.z, a2.w), pk2bf(a3.x, a3.y), pk2bf(a3.z, a3.w)};
        uint4 pb0 = {pk2bf(b0.x, b0.y), pk2bf(b0.z, b0.w), pk2bf(b1.x, b1.y), pk2bf(b1.z, b1.w)};
        uint4 pb1 = {pk2bf(b2.x, b2.y), pk2bf(b2.z, b2.w), pk2bf(b3.x, b3.y), pk2bf(b3.z, b3.w)};
        __syncthreads();
        *reinterpret_cast<uint4*>(&sA[tr * 40 + th])     = pa0;
        *reinterpret_cast<uint4*>(&sA[tr * 40 + th + 8]) = pa1;
        *reinterpret_cast<uint4*>(&sB[tr * 40 + th])     = pb0;
        *reinterpret_cast<uint4*>(&sB[tr * 40 + th + 8]) = pb1;
        __syncthreads();

        bf16x8 af[4], bfv[4];
#pragma unroll
        for (int m = 0; m < 4; ++m)
            af[m] = __builtin_bit_cast(bf16x8,
                *reinterpret_cast<const uint4*>(&sA[(wr * 64 + m * 16 + rl) * 40 + kq]));
#pragma unroll
        for (int n = 0; n < 4; ++n)
            bfv[n] = __builtin_bit_cast(bf16x8,
                *reinterpret_cast<const uint4*>(&sB[(wc * 64 + n * 16 + rl) * 40 + kq]));
#pragma unroll
        for (int m = 0; m < 4; ++m)
#pragma unroll
            for (int n = 0; n < 4; ++n)
                acc[m][n] = __builtin_amdgcn_mfma_f32_16x16x32_bf16(af[m], bfv[n], acc[m][n], 0, 0, 0);
    }

    const int rq = (lane >> 4) * 4;
#pragma unroll
    for (int m = 0; m < 4; ++m) {
        int r = bm + wr * 64 + m * 16 + rq;
#pragma unroll
        for (int n = 0; n < 4; ++n) {
            int c = bn + wc * 64 + n * 16 + rl;
#pragma unroll
            for (int reg = 0; reg < 4; ++reg)
                C[(size_t)(r + reg) * 512 + c] = f2bf(acc[m][n][reg] * scale);
        }
    }
}

// ---------------- fused flash attention, 32x32 MFMA, layout-invariant PV -------------
// grid: (16 q-tiles, 8 heads, 4 batch). block: 256 = 4 waves, each wave 32 q-rows.
// KV tile = 64. SCALE folded into Q, slope folded into staged positions.
// S^T: mfma(K,Q) -> D[row=j][col=q]: lane q=l&31, j=(r&3)+8*(r>>2)+4*hi (+32 for s1).
// QK^T operand map (both sides identical -> invariant): elem (hi,e) -> c=16ks+8hi+e.
// PV: P-frag is LANE-LOCAL: s-regs [8m..8m+7] pack to elem e with
//     j = 16ks + 4hi + (e&3) + 8*(e>>2); V-frag is loaded with the SAME map
//     (two b64 reads at 16ks+4hi and 16ks+8+4hi) -> invariant, no cross-lane ops.
__global__ __launch_bounds__(256, 2) void attn_fwd(const unsigned short* __restrict__ Q,
                                                   const unsigned short* __restrict__ Kb,
                                                   const unsigned short* __restrict__ Vt,
                                                   const float* __restrict__ pos,
                                                   float* __restrict__ Out) {
    __shared__ __align__(16) unsigned char smem[34816];
    unsigned short* sK = (unsigned short*)smem;        // [64][72]
    unsigned short* sV = sK + 64 * 72;                 // [64][72]
    float* sPos = (float*)(sV + 64 * 72);              // [64], pre-scaled by slope

    const int tid  = threadIdx.x;
    const int lane = tid & 63;
    const int w    = tid >> 6;
    const int l31  = lane & 31;
    const int hi   = lane >> 5;
    const int b = blockIdx.z, h = blockIdx.y;
    const int q0 = blockIdx.x * 128 + w * 32;
    const size_t rowbase = (size_t)b * 2048;
    const int hc = h * 64;
    const int bh = b * 8 + h;
    const float slope = ldexpf(1.0f, -(h + 1));

    // Q B-fragments: lane supplies Q[q=l31][c = ks*16 + hi*8 + e]
    bf16x8 qf0, qf1, qf2, qf3;
    {
        const unsigned short* qp = &Q[(rowbase + q0 + l31) * 512 + hc + hi * 8];
        qf0 = __builtin_bit_cast(bf16x8, *reinterpret_cast<const uint4*>(qp));
        qf1 = __builtin_bit_cast(bf16x8, *reinterpret_cast<const uint4*>(qp + 16));
        qf2 = __builtin_bit_cast(bf16x8, *reinterpret_cast<const uint4*>(qp + 32));
        qf3 = __builtin_bit_cast(bf16x8, *reinterpret_cast<const uint4*>(qp + 48));
    }
    const float ui = slope * pos[rowbase + q0 + l31];

    float mrun = -1e30f, lrun = 0.f;
    f32x16 o0, o1;
#pragma unroll
    for (int r = 0; r < 16; ++r) { o0[r] = 0.f; o1[r] = 0.f; }

    const int sr = tid >> 2;
    const int sq = (tid & 3) * 16;

    uint4 ck0, ck1, cv0, cv1;
    float cpj = 0.f;
    {
        size_t kgo = (rowbase + sr) * 512 + hc + sq;
        size_t vgo = ((size_t)bh * 64 + sr) * 2048 + sq;
        ck0 = *reinterpret_cast<const uint4*>(&Kb[kgo]);
        ck1 = *reinterpret_cast<const uint4*>(&Kb[kgo + 8]);
        cv0 = *reinterpret_cast<const uint4*>(&Vt[vgo]);
        cv1 = *reinterpret_cast<const uint4*>(&Vt[vgo + 8]);
        if (tid < 64) cpj = pos[rowbase + tid];
    }

    for (int j0 = 0; j0 < 2048; j0 += 64) {
        __syncthreads();  // WAR: all waves done with previous tile
        *reinterpret_cast<uint4*>(&sK[sr * 72 + sq])     = ck0;
        *reinterpret_cast<uint4*>(&sK[sr * 72 + sq + 8]) = ck1;
        *reinterpret_cast<uint4*>(&sV[sr * 72 + sq])     = cv0;
        *reinterpret_cast<uint4*>(&sV[sr * 72 + sq + 8]) = cv1;
        if (tid < 64) sPos[tid] = slope * cpj;
        if (j0 + 64 < 2048) {  // prefetch next tile; latency hides under compute
            size_t kgn = (rowbase + j0 + 64 + sr) * 512 + hc + sq;
            size_t vgn = ((size_t)bh * 64 + sr) * 2048 + j0 + 64 + sq;
            ck0 = *reinterpret_cast<const uint4*>(&Kb[kgn]);
            ck1 = *reinterpret_cast<const uint4*>(&Kb[kgn + 8]);
            cv0 = *reinterpret_cast<const uint4*>(&Vt[vgn]);
            cv1 = *reinterpret_cast<const uint4*>(&Vt[vgn + 8]);
            if (tid < 64) cpj = pos[rowbase + j0 + 64 + tid];
        }
        __syncthreads();  // tile ready

        // ---- S^T = K Q^T : two 32x32 accumulators (j-blocks 0..31, 32..63) ----
        f32x16 s0, s1;
#pragma unroll
        for (int r = 0; r < 16; ++r) { s0[r] = 0.f; s1[r] = 0.f; }
        __builtin_amdgcn_s_setprio(1);
#pragma unroll
        for (int ks = 0; ks < 4; ++ks) {
            bf16x8 k0 = __builtin_bit_cast(bf16x8,
                *reinterpret_cast<const uint4*>(&sK[l31 * 72 + ks * 16 + hi * 8]));
            bf16x8 k1 = __builtin_bit_cast(bf16x8,
                *reinterpret_cast<const uint4*>(&sK[(32 + l31) * 72 + ks * 16 + hi * 8]));
            bf16x8 qq = (ks == 0) ? qf0 : (ks == 1) ? qf1 : (ks == 2) ? qf2 : qf3;
            s0 = __builtin_amdgcn_mfma_f32_32x32x16_bf16(k0, qq, s0, 0, 0, 0);
            s1 = __builtin_amdgcn_mfma_f32_32x32x16_bf16(k1, qq, s1, 0, 0, 0);
        }
        __builtin_amdgcn_s_setprio(0);

        // ---- bias + lane-local online softmax (defer-max, THR=8) ----
        float pmax = -1e30f;
#pragma unroll
        for (int t = 0; t < 4; ++t) {
            f32x4 u0 = *reinterpret_cast<const f32x4*>(&sPos[8 * t + 4 * hi]);
            f32x4 u1 = *reinterpret_cast<const f32x4*>(&sPos[32 + 8 * t + 4 * hi]);
#pragma unroll
            for (int r = 0; r < 4; ++r) {
                float v0 = s0[4 * t + r] - fabsf(u0[r] - ui);
                float v1 = s1[4 * t + r] - fabsf(u1[r] - ui);
                s0[4 * t + r] = v0;
                s1[4 * t + r] = v1;
                pmax = fmaxf(pmax, fmaxf(v0, v1));
            }
        }
        pmax = fmaxf(pmax, __shfl_xor(pmax, 32, 64));  // combine partner half (same q)
        if (__any(pmax > mrun + 8.0f)) {
            float mnew = fmaxf(mrun, pmax);
            float alpha = __expf(mrun - mnew);
            mrun = mnew;
            lrun *= alpha;
#pragma unroll
            for (int r = 0; r < 16; ++r) { o0[r] *= alpha; o1[r] *= alpha; }
        }
        float ls = 0.f;
#pragma unroll
        for (int r = 0; r < 16; ++r) {
            float p0 = __expf(s0[r] - mrun);
            float p1 = __expf(s1[r] - mrun);
            s0[r] = p0; s1[r] = p1;
            ls += p0 + p1;
        }
        ls += __shfl_xor(ls, 32, 64);
        lrun += ls;

        // ---- lane-local P fragments: elem e -> j = 16ks + 4hi + (e&3) + 8*(e>>2) ----
        bf16x8 pf0 = __builtin_bit_cast(bf16x8, (uint4){
            pk2bf(s0[0], s0[1]),  pk2bf(s0[2], s0[3]),  pk2bf(s0[4], s0[5]),   pk2bf(s0[6], s0[7])});
        bf16x8 pf1 = __builtin_bit_cast(bf16x8, (uint4){
            pk2bf(s0[8], s0[9]),  pk2bf(s0[10], s0[11]), pk2bf(s0[12], s0[13]), pk2bf(s0[14], s0[15])});
        bf16x8 pf2 = __builtin_bit_cast(bf16x8, (uint4){
            pk2bf(s1[0], s1[1]),  pk2bf(s1[2], s1[3]),  pk2bf(s1[4], s1[5]),   pk2bf(s1[6], s1[7])});
        bf16x8 pf3 = __builtin_bit_cast(bf16x8, (uint4){
            pk2bf(s1[8], s1[9]),  pk2bf(s1[10], s1[11]), pk2bf(s1[12], s1[13]), pk2bf(s1[14], s1[15])});

        // ---- PV: O^T[d][q] += Vt-frag x P-frag (V loaded with the SAME j-map) ----
        __builtin_amdgcn_s_setprio(1);
#pragma unroll
        for (int ks = 0; ks < 4; ++ks) {
            uint2 a0 = *reinterpret_cast<const uint2*>(&sV[l31 * 72 + ks * 16 + 4 * hi]);
            uint2 a1 = *reinterpret_cast<const uint2*>(&sV[l31 * 72 + ks * 16 + 8 + 4 * hi]);
            uint2 b0 = *reinterpret_cast<const uint2*>(&sV[(32 + l31) * 72 + ks * 16 + 4 * hi]);
            uint2 b1 = *reinterpret_cast<const uint2*>(&sV[(32 + l31) * 72 + ks * 16 + 8 + 4 * hi]);
            bf16x8 v0 = __builtin_bit_cast(bf16x8, (uint4){a0.x, a0.y, a1.x, a1.y});
            bf16x8 v1 = __builtin_bit_cast(bf16x8, (uint4){b0.x, b0.y, b1.x, b1.y});
            bf16x8 pf = (ks == 0) ? pf0 : (ks == 1) ? pf1 : (ks == 2) ? pf2 : pf3;
            o0 = __builtin_amdgcn_mfma_f32_32x32x16_bf16(v0, pf, o0, 0, 0, 0);
            o1 = __builtin_amdgcn_mfma_f32_32x32x16_bf16(v1, pf, o1, 0, 0, 0);
        }
        __builtin_amdgcn_s_setprio(0);
    }

    // ---- epilogue: normalize (lane-local), transpose via LDS, coalesced store ----
    const float linv = 1.0f / lrun;
    __syncthreads();  // done reading sK/sV; safe to alias
    float* sO = (float*)smem + w * (32 * 68);  // per-wave [32 q][68 pad] f32
#pragma unroll
    for (int t = 0; t < 4; ++t) {
        f32x4 v0, v1;
#pragma unroll
        for (int r = 0; r < 4; ++r) { v0[r] = o0[4 * t + r] * linv; v1[r] = o1[4 * t + r] * linv; }
        *reinterpret_cast<f32x4*>(&sO[l31 * 68 + 8 * t + 4 * hi])      = v0;
        *reinterpret_cast<f32x4*>(&sO[l31 * 68 + 32 + 8 * t + 4 * hi]) = v1;
    }
    // wave-private region: compiler inserts lgkmcnt wait for the dependent reads
#pragma unroll
    for (int rr = 0; rr < 8; ++rr) {
        int qr = rr * 4 + (lane >> 4);
        int ch = lane & 15;
        f32x4 v = *reinterpret_cast<const f32x4*>(&sO[qr * 68 + ch * 4]);
        *reinterpret_cast<f32x4*>(&Out[(rowbase + q0 + qr) * 512 + hc + ch * 4]) = v;
    }
}

extern "C" void kernel_launch(void* const* d_in, const int* in_sizes, int n_in,
                              void* d_out, int out_size, void* d_ws, size_t ws_size,
                              hipStream_t stream) {
    const float* x   = (const float*)d_in[0];
    const float* pos = (const float*)d_in[1];
    const float* Wq  = (const float*)d_in[2];
    const float* Wk  = (const float*)d_in[3];
    float* out = (float*)d_out;

    // ws (bf16 elems): Q 4.19M | K 4.19M | Vt 4.19M  (~25MB)
    unsigned short* Qb  = (unsigned short*)d_ws;
    unsigned short* Kbf = Qb  + 4194304;
    unsigned short* Vtb = Kbf + 4194304;

    xpose_v<<<dim3(8, 8, 4), dim3(256), 0, stream>>>(x, Vtb);
    gemm_qk<<<dim3(64, 8), dim3(256), 0, stream>>>(x, Wq, Wk, Qb, Kbf);
    attn_fwd<<<dim3(16, 8, 4), dim3(256), 0, stream>>>(Qb, Kbf, Vtb, pos, out);
}

// Round 6
// 89.276 us; speedup vs baseline: 2.0578x; 1.0958x over previous
//
#include <hip/hip_runtime.h>
#include <hip/hip_bf16.h>

typedef __bf16 bf16x8 __attribute__((ext_vector_type(8)));
typedef float f32x4 __attribute__((ext_vector_type(4)));
typedef float f32x16 __attribute__((ext_vector_type(16)));

__device__ inline unsigned short f2bf(float f) {
    __hip_bfloat16 h = __float2bfloat16(f);
    return __builtin_bit_cast(unsigned short, h);
}
__device__ inline unsigned pk2bf(float a, float b) {
    return (unsigned)f2bf(a) | ((unsigned)f2bf(b) << 16);
}
__device__ inline float exp2_fast(float x) {
    float r;
    asm("v_exp_f32 %0, %1" : "=v"(r) : "v"(x));
    return r;
}

#define QSCALE 0.1803368801111244f  /* 0.125 * log2(e) */

// ---------------- V transpose: x[b][n][hc+d] (f32) -> Vt[b*8+h][d][n] (bf16) ---------
__global__ __launch_bounds__(256) void xpose_v(const float* __restrict__ x,
                                               unsigned short* __restrict__ Vt) {
    const int tid = threadIdx.x;
    const int lane = tid & 63, w = tid >> 6;
    const int b = blockIdx.z, h = blockIdx.y;
    const int n = blockIdx.x * 256 + w * 64 + lane;
    const size_t xrow = ((size_t)b * 2048 + n) * 512 + h * 64;
    const size_t vbase = ((size_t)(b * 8 + h) * 64) * 2048 + n;
#pragma unroll
    for (int d0 = 0; d0 < 64; d0 += 4) {
        float4 v = *reinterpret_cast<const float4*>(&x[xrow + d0]);
        Vt[vbase + (size_t)(d0 + 0) * 2048] = f2bf(v.x);
        Vt[vbase + (size_t)(d0 + 1) * 2048] = f2bf(v.y);
        Vt[vbase + (size_t)(d0 + 2) * 2048] = f2bf(v.z);
        Vt[vbase + (size_t)(d0 + 3) * 2048] = f2bf(v.w);
    }
}

// ---------------- fused Q/K projection: C = x(8192x512) * W^T, f32 in, bf16 out ------
// grid (64, 8): by<4 -> Wq (0.125*log2e folded), by>=4 -> Wk. 128x128 tile, 4 waves.
__global__ __launch_bounds__(256) void gemm_qk(const float* __restrict__ x,
                                               const float* __restrict__ Wq,
                                               const float* __restrict__ Wk,
                                               unsigned short* __restrict__ Qb,
                                               unsigned short* __restrict__ Kb) {
    __shared__ __align__(16) unsigned short sA[128 * 40];
    __shared__ __align__(16) unsigned short sB[128 * 40];
    const int tid  = threadIdx.x;
    const int lane = tid & 63;
    const int wave = tid >> 6;
    const int wr = wave >> 1, wc = wave & 1;
    const int bm = blockIdx.x * 128;
    const int by = blockIdx.y;
    const float* __restrict__ Bsrc = (by < 4) ? Wq : Wk;
    unsigned short* __restrict__ C = (by < 4) ? Qb : Kb;
    const int bn = (by & 3) * 128;
    const float scale = (by < 4) ? QSCALE : 1.0f;
    const int tr = tid >> 1, th = (tid & 1) * 16;
    const int rl = lane & 15;
    const int kq = (lane >> 4) * 8;

    f32x4 acc[4][4];
#pragma unroll
    for (int m = 0; m < 4; ++m)
#pragma unroll
        for (int n = 0; n < 4; ++n) acc[m][n] = (f32x4){0.f, 0.f, 0.f, 0.f};

    for (int k0 = 0; k0 < 512; k0 += 32) {
        const float* ap = &x[(size_t)(bm + tr) * 512 + k0 + th];
        const float* bp = &Bsrc[(size_t)(bn + tr) * 512 + k0 + th];
        float4 a0 = *reinterpret_cast<const float4*>(ap);
        float4 a1 = *reinterpret_cast<const float4*>(ap + 4);
        float4 a2 = *reinterpret_cast<const float4*>(ap + 8);
        float4 a3 = *reinterpret_cast<const float4*>(ap + 12);
        float4 b0 = *reinterpret_cast<const float4*>(bp);
        float4 b1 = *reinterpret_cast<const float4*>(bp + 4);
        float4 b2 = *reinterpret_cast<const float4*>(bp + 8);
        float4 b3 = *reinterpret_cast<const float4*>(bp + 12);
        uint4 pa0 = {pk2bf(a0.x, a0.y), pk2bf(a0.z, a0.w), pk2bf(a1.x, a1.y), pk2bf(a1.z, a1.w)};
        uint4 pa1 = {pk2bf(a2.x, a2.y), pk2bf(a2.z, a2.w), pk2bf(a3.x, a3.y), pk2bf(a3.z, a3.w)};
        uint4 pb0 = {pk2bf(b0.x, b0.y), pk2bf(b0.z, b0.w), pk2bf(b1.x, b1.y), pk2bf(b1.z, b1.w)};
        uint4 pb1 = {pk2bf(b2.x, b2.y), pk2bf(b2.z, b2.w), pk2bf(b3.x, b3.y), pk2bf(b3.z, b3.w)};
        __syncthreads();
        *reinterpret_cast<uint4*>(&sA[tr * 40 + th])     = pa0;
        *reinterpret_cast<uint4*>(&sA[tr * 40 + th + 8]) = pa1;
        *reinterpret_cast<uint4*>(&sB[tr * 40 + th])     = pb0;
        *reinterpret_cast<uint4*>(&sB[tr * 40 + th + 8]) = pb1;
        __syncthreads();

        bf16x8 af[4], bfv[4];
#pragma unroll
        for (int m = 0; m < 4; ++m)
            af[m] = __builtin_bit_cast(bf16x8,
                *reinterpret_cast<const uint4*>(&sA[(wr * 64 + m * 16 + rl) * 40 + kq]));
#pragma unroll
        for (int n = 0; n < 4; ++n)
            bfv[n] = __builtin_bit_cast(bf16x8,
                *reinterpret_cast<const uint4*>(&sB[(wc * 64 + n * 16 + rl) * 40 + kq]));
#pragma unroll
        for (int m = 0; m < 4; ++m)
#pragma unroll
            for (int n = 0; n < 4; ++n)
                acc[m][n] = __builtin_amdgcn_mfma_f32_16x16x32_bf16(af[m], bfv[n], acc[m][n], 0, 0, 0);
    }

    const int rq = (lane >> 4) * 4;
#pragma unroll
    for (int m = 0; m < 4; ++m) {
        int r = bm + wr * 64 + m * 16 + rq;
#pragma unroll
        for (int n = 0; n < 4; ++n) {
            int c = bn + wc * 64 + n * 16 + rl;
#pragma unroll
            for (int reg = 0; reg < 4; ++reg)
                C[(size_t)(r + reg) * 512 + c] = f2bf(acc[m][n][reg] * scale);
        }
    }
}

// ---------------- fused flash attention, 8 waves, j-parity split, fixed-ref exp2 -----
// grid: (16 q-tiles, 8 heads, 4 batch). block: 512 = 8 waves.
// Wave w: q-sub-tile qh=w&3 (32 rows), j-parity jp=w>>2 (every other 32-j chunk).
// No online max: S' is in log2 domain (log2e folded into Q-scale and slope); P=exp2(S').
// Parity partials (O, l) add directly; merged via LDS in epilogue.
// S^T: mfma(K,Q) -> D[row=j][col=q]: lane q=l31, j=(r&3)+8*(r>>2)+4*hi.
// PV: P-frag lane-local, j-map = 16ks + 4hi + (e&3) + 8*(e>>2); V-frag loaded same map.
// sK/sV: [64][64] bf16 rows, XOR-swizzled (byte ^= (row&7)<<4) write AND read.
__global__ __launch_bounds__(512, 4) void attn_fwd(const unsigned short* __restrict__ Q,
                                                   const unsigned short* __restrict__ Kb,
                                                   const unsigned short* __restrict__ Vt,
                                                   const float* __restrict__ pos,
                                                   float* __restrict__ Out) {
    __shared__ __align__(16) unsigned char smem[51456];
    unsigned short* sK = (unsigned short*)smem;            // [64][64] swizzled (8 KiB)
    unsigned short* sV = (unsigned short*)(smem + 8192);   // [64][64] swizzled (8 KiB)
    float* sPos = (float*)(smem + 16384);                  // [64] slope'*pos
    float* sM   = (float*)(smem + 16640);                  // 34816 B merge/transpose

    const int tid  = threadIdx.x;
    const int lane = tid & 63;
    const int w    = tid >> 6;      // 0..7
    const int l31  = lane & 31;
    const int hi   = lane >> 5;
    const int qh   = w & 3;
    const int jp   = w >> 2;
    const int b = blockIdx.z, h = blockIdx.y;
    const int q0 = blockIdx.x * 128 + qh * 32;
    const size_t rowbase = (size_t)b * 2048;
    const int hc = h * 64;
    const int bh = b * 8 + h;
    const float slopeL = ldexpf(1.4426950408889634f, -(h + 1));  // slope * log2(e)

    // Q B-fragments: lane supplies Q[q=l31][c = ks*16 + hi*8 + e] (Q pre-scaled)
    bf16x8 qf0, qf1, qf2, qf3;
    {
        const unsigned short* qp = &Q[(rowbase + q0 + l31) * 512 + hc + hi * 8];
        qf0 = __builtin_bit_cast(bf16x8, *reinterpret_cast<const uint4*>(qp));
        qf1 = __builtin_bit_cast(bf16x8, *reinterpret_cast<const uint4*>(qp + 16));
        qf2 = __builtin_bit_cast(bf16x8, *reinterpret_cast<const uint4*>(qp + 32));
        qf3 = __builtin_bit_cast(bf16x8, *reinterpret_cast<const uint4*>(qp + 48));
    }
    const float ui = slopeL * pos[rowbase + q0 + l31];

    float lloc = 0.f;
    f32x16 o0, o1;
#pragma unroll
    for (int r = 0; r < 16; ++r) { o0[r] = 0.f; o1[r] = 0.f; }

    // staging: 512 threads, one uint4 each per buffer
    const int sr  = tid >> 3;                          // row 0..63
    const int sqe = (tid & 7) * 8;                     // elem col
    const int wbyte = sr * 128 + (((tid & 7) * 16) ^ ((sr & 7) << 4));
    const int kswz = (l31 & 7) << 4;                   // read-side swizzle key
    const char* sKrow = (const char*)sK + (32 * jp + l31) * 128;
    const char* sVr0  = (const char*)sV + l31 * 128;
    const char* sVr1  = (const char*)sV + (32 + l31) * 128;
    const int vb = 64 * jp;                            // byte col of parity chunk in V row

    uint4 ck, cv;
    float cpj = 0.f;
    {
        ck = *reinterpret_cast<const uint4*>(&Kb[(rowbase + sr) * 512 + hc + sqe]);
        cv = *reinterpret_cast<const uint4*>(&Vt[((size_t)bh * 64 + sr) * 2048 + sqe]);
        if (tid < 64) cpj = pos[rowbase + tid];
    }

    for (int j0 = 0; j0 < 2048; j0 += 64) {
        __syncthreads();  // WAR: all waves done with previous tile
        *reinterpret_cast<uint4*>((char*)sK + wbyte) = ck;
        *reinterpret_cast<uint4*>((char*)sV + wbyte) = cv;
        if (tid < 64) sPos[tid] = slopeL * cpj;
        if (j0 + 64 < 2048) {  // prefetch next tile
            ck = *reinterpret_cast<const uint4*>(&Kb[(rowbase + j0 + 64 + sr) * 512 + hc + sqe]);
            cv = *reinterpret_cast<const uint4*>(&Vt[((size_t)bh * 64 + sr) * 2048 + j0 + 64 + sqe]);
            if (tid < 64) cpj = pos[rowbase + j0 + 64 + tid];
        }
        __syncthreads();  // tile ready

        // ---- S chunk (32j x 32q) for this wave's parity ----
        f32x16 s;
#pragma unroll
        for (int r = 0; r < 16; ++r) s[r] = 0.f;
        __builtin_amdgcn_s_setprio(1);
#pragma unroll
        for (int ks = 0; ks < 4; ++ks) {
            bf16x8 kf = __builtin_bit_cast(bf16x8,
                *reinterpret_cast<const uint4*>(sKrow + ((ks * 32 + hi * 16) ^ kswz)));
            bf16x8 qq = (ks == 0) ? qf0 : (ks == 1) ? qf1 : (ks == 2) ? qf2 : qf3;
            s = __builtin_amdgcn_mfma_f32_32x32x16_bf16(kf, qq, s, 0, 0, 0);
        }
        __builtin_amdgcn_s_setprio(0);

        // ---- bias + exp2 (fixed reference, no max tracking) ----
        float ls = 0.f;
#pragma unroll
        for (int t = 0; t < 4; ++t) {
            f32x4 u = *reinterpret_cast<const f32x4*>(&sPos[32 * jp + 8 * t + 4 * hi]);
#pragma unroll
            for (int r = 0; r < 4; ++r) {
                float v = s[4 * t + r] - fabsf(u[r] - ui);
                float p = exp2_fast(v);
                s[4 * t + r] = p;
                ls += p;
            }
        }
        lloc += ls;

        // ---- lane-local P fragments (j = 16ks + 4hi + (e&3) + 8*(e>>2)) ----
        bf16x8 pf0 = __builtin_bit_cast(bf16x8, (uint4){
            pk2bf(s[0], s[1]),  pk2bf(s[2], s[3]),   pk2bf(s[4], s[5]),   pk2bf(s[6], s[7])});
        bf16x8 pf1 = __builtin_bit_cast(bf16x8, (uint4){
            pk2bf(s[8], s[9]),  pk2bf(s[10], s[11]), pk2bf(s[12], s[13]), pk2bf(s[14], s[15])});

        // ---- PV: O^T[d][q] += Vt-frag x P-frag (V loaded with the SAME j-map) ----
        __builtin_amdgcn_s_setprio(1);
#pragma unroll
        for (int ks = 0; ks < 2; ++ks) {
            const int cb = vb + ks * 32 + hi * 8;
            uint2 a0 = *reinterpret_cast<const uint2*>(sVr0 + (cb ^ kswz));
            uint2 a1 = *reinterpret_cast<const uint2*>(sVr0 + ((cb + 16) ^ kswz));
            uint2 b0 = *reinterpret_cast<const uint2*>(sVr1 + (cb ^ kswz));
            uint2 b1 = *reinterpret_cast<const uint2*>(sVr1 + ((cb + 16) ^ kswz));
            bf16x8 v0 = __builtin_bit_cast(bf16x8, (uint4){a0.x, a0.y, a1.x, a1.y});
            bf16x8 v1 = __builtin_bit_cast(bf16x8, (uint4){b0.x, b0.y, b1.x, b1.y});
            bf16x8 pf = ks ? pf1 : pf0;
            o0 = __builtin_amdgcn_mfma_f32_32x32x16_bf16(v0, pf, o0, 0, 0, 0);
            o1 = __builtin_amdgcn_mfma_f32_32x32x16_bf16(v1, pf, o1, 0, 0, 0);
        }
        __builtin_amdgcn_s_setprio(0);
    }

    // ---- epilogue: merge parity partials, normalize, transpose-store ----
    float lt = lloc + __shfl_xor(lloc, 32, 64);  // combine hi halves (same q)
    __syncthreads();
    if (w >= 4) {  // parity-1 waves dump partials (XOR-swizzled rows: conflict-free)
        float* dst = sM + (size_t)(w - 4) * 2048 + lane * 32;
        const int key = (lane & 7) << 2;
#pragma unroll
        for (int i = 0; i < 4; ++i) {
            f32x4 t0 = {o0[4 * i], o0[4 * i + 1], o0[4 * i + 2], o0[4 * i + 3]};
            f32x4 t1 = {o1[4 * i], o1[4 * i + 1], o1[4 * i + 2], o1[4 * i + 3]};
            *reinterpret_cast<f32x4*>(dst + ((4 * i) ^ key))      = t0;
            *reinterpret_cast<f32x4*>(dst + ((16 + 4 * i) ^ key)) = t1;
        }
        sM[8192 + (w - 4) * 64 + lane] = lt;
    }
    __syncthreads();
    float linv = 0.f;
    if (w < 4) {  // parity-0 waves: add partner partial, normalize
        const float* src = sM + (size_t)w * 2048 + lane * 32;
        const int key = (lane & 7) << 2;
#pragma unroll
        for (int i = 0; i < 4; ++i) {
            f32x4 t0 = *reinterpret_cast<const f32x4*>(src + ((4 * i) ^ key));
            f32x4 t1 = *reinterpret_cast<const f32x4*>(src + ((16 + 4 * i) ^ key));
#pragma unroll
            for (int r = 0; r < 4; ++r) { o0[4 * i + r] += t0[r]; o1[4 * i + r] += t1[r]; }
        }
        linv = 1.0f / (lt + sM[8192 + w * 64 + lane]);
    }
    __syncthreads();
    if (w < 4) {
        float* sO = sM + w * (32 * 68);  // per-wave [32 q][68 pad] f32
#pragma unroll
        for (int t = 0; t < 4; ++t) {
            f32x4 v0, v1;
#pragma unroll
            for (int r = 0; r < 4; ++r) {
                v0[r] = o0[4 * t + r] * linv;
                v1[r] = o1[4 * t + r] * linv;
            }
            *reinterpret_cast<f32x4*>(&sO[l31 * 68 + 8 * t + 4 * hi])      = v0;
            *reinterpret_cast<f32x4*>(&sO[l31 * 68 + 32 + 8 * t + 4 * hi]) = v1;
        }
        // wave-private region: compiler inserts lgkmcnt wait for dependent reads
#pragma unroll
        for (int rr = 0; rr < 8; ++rr) {
            int qr = rr * 4 + (lane >> 4);
            int ch = lane & 15;
            f32x4 v = *reinterpret_cast<const f32x4*>(&sO[qr * 68 + ch * 4]);
            *reinterpret_cast<f32x4*>(&Out[(rowbase + q0 + qr) * 512 + hc + ch * 4]) = v;
        }
    }
}

extern "C" void kernel_launch(void* const* d_in, const int* in_sizes, int n_in,
                              void* d_out, int out_size, void* d_ws, size_t ws_size,
                              hipStream_t stream) {
    const float* x   = (const float*)d_in[0];
    const float* pos = (const float*)d_in[1];
    const float* Wq  = (const float*)d_in[2];
    const float* Wk  = (const float*)d_in[3];
    float* out = (float*)d_out;

    // ws (bf16 elems): Q 4.19M | K 4.19M | Vt 4.19M  (~25MB)
    unsigned short* Qb  = (unsigned short*)d_ws;
    unsigned short* Kbf = Qb  + 4194304;
    unsigned short* Vtb = Kbf + 4194304;

    xpose_v<<<dim3(8, 8, 4), dim3(256), 0, stream>>>(x, Vtb);
    gemm_qk<<<dim3(64, 8), dim3(256), 0, stream>>>(x, Wq, Wk, Qb, Kbf);
    attn_fwd<<<dim3(16, 8, 4), dim3(512), 0, stream>>>(Qb, Kbf, Vtb, pos, out);
}